// Round 4
// baseline (1146.011 us; speedup 1.0000x reference)
//
#include <hip/hip_runtime.h>
#include <stdint.h>

__device__ __forceinline__ float bf2f(unsigned short b) {
    union { unsigned u; float f; } c; c.u = ((unsigned)b) << 16; return c.f;
}
__device__ __forceinline__ unsigned short f2bf(float f) {
    union { float f; unsigned u; } c; c.f = f;
    unsigned u = c.u;
    u += 0x7fffu + ((u >> 16) & 1u);          // round-to-nearest-even
    return (unsigned short)(u >> 16);
}

// Keep the harness-named symbol just in case anything looks it up.
__global__ void GNNEncoder_317827579954_kernel() {}

// Sentinel: 0x3F803F80 = bf16{1.0,1.0} = f32 1.00392... Distinguishes
// "kernels never ran" (output stays 0) from "pipeline wrong" in the bench error.
__global__ void k_sentinel(unsigned* __restrict__ out, int nwords) {
    int i = blockIdx.x * 256 + threadIdx.x;
    if (i < nwords) out[i] = 0x3F803F80u;
}

__global__ void k_zero(int* __restrict__ p, int n) {
    int i = blockIdx.x * 256 + threadIdx.x;
    if (i < n) p[i] = 0;
}

// flags[0] = 1 if x is f32 (else bf16-packed); flags[1] = 1 if edge_index is int64.
__global__ void k_flags(const unsigned* __restrict__ x, const int* __restrict__ ei,
                        int E, int* __restrict__ flags) {
    if (threadIdx.x != 0 || blockIdx.x != 0) return;
    // x test: low ushort of each word. bf16-packed -> plausible bf16 exponent.
    // f32 -> low half is uniform mantissa bits (~18% plausible).
    int plausible = 0;
    for (int i = 0; i < 256; ++i) {
        unsigned u = x[i] & 0xffffu;
        unsigned e = (u >> 7) & 0xffu;
        if ((e >= 100u && e <= 145u) || u == 0u) ++plausible;
    }
    flags[0] = (plausible >= 192) ? 0 : 1;   // 0 = bf16, 1 = f32
    int n = E < 128 ? E : 128;
    int is64 = 1;
    for (int i = 0; i < n; ++i) {
        if (ei[2 * i + 1] != 0) { is64 = 0; break; }
    }
    flags[1] = is64;
}

// Normalize any dense input into bf16 workspace.
__global__ void k_cvt(const void* __restrict__ in, unsigned short* __restrict__ out,
                      int n, const int* __restrict__ flags) {
    int i = blockIdx.x * 256 + threadIdx.x;
    if (i >= n) return;
    if (flags[0]) out[i] = f2bf(((const float*)in)[i]);
    else          out[i] = ((const unsigned short*)in)[i];
}

// deg[v] = #(dst == v)
__global__ void k_count(const int* __restrict__ ei, int E, const int* __restrict__ flags,
                        int* __restrict__ deg) {
    int i = blockIdx.x * blockDim.x + threadIdx.x;
    if (i >= E) return;
    int d = flags[1] ? ei[2 * E + 2 * i] : ei[E + i];
    atomicAdd(&deg[d], 1);
}

// single-block exclusive scan -> offs, cursor, dinv = rsqrt(deg+1)
__global__ void k_scan(const int* __restrict__ deg, int* __restrict__ offs,
                       int* __restrict__ cursor, float* __restrict__ dinv, int N) {
    __shared__ int sums[256];
    __shared__ int pref[257];
    int t = threadIdx.x;
    int chunk = (N + 255) / 256;
    int lo = t * chunk;
    int hi = lo + chunk; if (hi > N) hi = N;
    int s = 0;
    for (int i = lo; i < hi; ++i) s += deg[i];
    sums[t] = s;
    __syncthreads();
    if (t == 0) {
        int run = 0;
        for (int i = 0; i < 256; ++i) { pref[i] = run; run += sums[i]; }
        pref[256] = run;
    }
    __syncthreads();
    int run = pref[t];
    for (int i = lo; i < hi; ++i) {
        offs[i] = run; cursor[i] = run;
        run += deg[i];
        dinv[i] = rsqrtf((float)(deg[i] + 1));   // +1 = self loop
    }
    if (t == 0) offs[N] = pref[256];
}

// counting-sort CSR fill: csr[slot(dst)] = src
__global__ void k_fill(const int* __restrict__ ei, int E, const int* __restrict__ flags,
                       int* __restrict__ cursor, int* __restrict__ csr) {
    int i = blockIdx.x * blockDim.x + threadIdx.x;
    if (i >= E) return;
    int s, d;
    if (flags[1]) { s = ei[2 * i];     d = ei[2 * E + 2 * i]; }
    else          { s = ei[i];         d = ei[E + i]; }
    int p = atomicAdd(&cursor[d], 1);
    csr[p] = s;
}

// C[M,256] = A[M,256] @ B[256,256]; bf16 in/out, fp32 acc. Pure VALU.
__global__ __launch_bounds__(256) void k_gemm(const unsigned short* __restrict__ A,
                                              const unsigned short* __restrict__ B,
                                              unsigned short* __restrict__ C, int M) {
    __shared__ unsigned short As[64][72];
    __shared__ unsigned short Bs[64][72];
    int t  = threadIdx.x;
    int tx = t & 15;
    int ty = t >> 4;
    int rowBase = blockIdx.x * 64;
    int colBase = blockIdx.y * 64;
    int r0 = ty * 4;
    int c0 = tx * 4;

    float acc[4][4] = {};
    int lrow = t >> 2;
    int lseg = t & 3;

    for (int kk = 0; kk < 256; kk += 64) {
        int arow = rowBase + lrow; if (arow >= M) arow = M - 1;
        const uint4* ag = (const uint4*)(A + (size_t)arow * 256 + kk + lseg * 8);
        *(uint4*)&As[lrow][lseg * 8]      = ag[0];
        *(uint4*)&As[lrow][lseg * 8 + 32] = ag[4];
        const uint4* bg = (const uint4*)(B + (size_t)(kk + lrow) * 256 + colBase + lseg * 8);
        *(uint4*)&Bs[lrow][lseg * 8]      = bg[0];
        *(uint4*)&Bs[lrow][lseg * 8 + 32] = bg[4];
        __syncthreads();

#pragma unroll 8
        for (int k = 0; k < 64; k += 2) {
            uint2 bq0 = *(const uint2*)&Bs[k][c0];
            uint2 bq1 = *(const uint2*)&Bs[k + 1][c0];
            float b00 = bf2f((unsigned short)(bq0.x & 0xffffu));
            float b01 = bf2f((unsigned short)(bq0.x >> 16));
            float b02 = bf2f((unsigned short)(bq0.y & 0xffffu));
            float b03 = bf2f((unsigned short)(bq0.y >> 16));
            float b10 = bf2f((unsigned short)(bq1.x & 0xffffu));
            float b11 = bf2f((unsigned short)(bq1.x >> 16));
            float b12 = bf2f((unsigned short)(bq1.y & 0xffffu));
            float b13 = bf2f((unsigned short)(bq1.y >> 16));
#pragma unroll
            for (int i = 0; i < 4; ++i) {
                unsigned a01 = *(const unsigned*)&As[r0 + i][k];
                float aE = bf2f((unsigned short)(a01 & 0xffffu));
                float aO = bf2f((unsigned short)(a01 >> 16));
                acc[i][0] += aE * b00 + aO * b10;
                acc[i][1] += aE * b01 + aO * b11;
                acc[i][2] += aE * b02 + aO * b12;
                acc[i][3] += aE * b03 + aO * b13;
            }
        }
        __syncthreads();
    }

#pragma unroll
    for (int i = 0; i < 4; ++i) {
        int rg = rowBase + r0 + i;
        if (rg < M) {
            uint2 o;
            o.x = (unsigned)f2bf(acc[i][0]) | ((unsigned)f2bf(acc[i][1]) << 16);
            o.y = (unsigned)f2bf(acc[i][2]) | ((unsigned)f2bf(acc[i][3]) << 16);
            *(uint2*)(C + (size_t)rg * 256 + colBase + c0) = o;
        }
    }
}

// out[v] = dinv[v]*sum_e dinv[src]*XW[src] + dinv[v]^2*XW[v] + b  (+relu)
// final=0 -> bf16 store (internal); final=1 -> store per flags[0] (f32 or bf16).
__global__ __launch_bounds__(256) void k_agg(const unsigned short* __restrict__ XW,
                                             const int* __restrict__ csr,
                                             const int* __restrict__ offs,
                                             const float* __restrict__ dinv,
                                             const unsigned short* __restrict__ bias,
                                             void* __restrict__ out,
                                             int relu, int final_, const int* __restrict__ flags,
                                             int N) {
    int v = blockIdx.x * 4 + (threadIdx.x >> 6);
    if (v >= N) return;
    int lane = threadIdx.x & 63;
    int c = lane * 4;
    float a0 = 0.f, a1 = 0.f, a2 = 0.f, a3 = 0.f;
    int beg = offs[v], end = offs[v + 1];
    for (int e = beg; e < end; ++e) {
        int s = csr[e];
        float w = dinv[s];
        uint2 u = *(const uint2*)(XW + (size_t)s * 256 + c);
        a0 += w * bf2f((unsigned short)(u.x & 0xffffu));
        a1 += w * bf2f((unsigned short)(u.x >> 16));
        a2 += w * bf2f((unsigned short)(u.y & 0xffffu));
        a3 += w * bf2f((unsigned short)(u.y >> 16));
    }
    float dv = dinv[v];
    float dv2 = dv * dv;
    uint2 su = *(const uint2*)(XW + (size_t)v * 256 + c);
    float r0 = dv * a0 + dv2 * bf2f((unsigned short)(su.x & 0xffffu)) + bf2f(bias[c + 0]);
    float r1 = dv * a1 + dv2 * bf2f((unsigned short)(su.x >> 16))     + bf2f(bias[c + 1]);
    float r2 = dv * a2 + dv2 * bf2f((unsigned short)(su.y & 0xffffu)) + bf2f(bias[c + 2]);
    float r3 = dv * a3 + dv2 * bf2f((unsigned short)(su.y >> 16))     + bf2f(bias[c + 3]);
    if (relu) {
        r0 = fmaxf(r0, 0.f); r1 = fmaxf(r1, 0.f);
        r2 = fmaxf(r2, 0.f); r3 = fmaxf(r3, 0.f);
    }
    if (final_ && flags[0]) {
        float4 o; o.x = r0; o.y = r1; o.z = r2; o.w = r3;
        *(float4*)((float*)out + (size_t)v * 256 + c) = o;
    } else {
        uint2 o;
        o.x = (unsigned)f2bf(r0) | ((unsigned)f2bf(r1) << 16);
        o.y = (unsigned)f2bf(r2) | ((unsigned)f2bf(r3) << 16);
        *(uint2*)((unsigned short*)out + (size_t)v * 256 + c) = o;
    }
}

extern "C" void kernel_launch(void* const* d_in, const int* in_sizes, int n_in,
                              void* d_out, int out_size, void* d_ws, size_t ws_size,
                              hipStream_t stream) {
    (void)n_in; (void)ws_size;
    const void* x  = d_in[0];
    const int*  ei = (const int*)d_in[1];
    const void* W1 = d_in[2];
    const void* b1 = d_in[3];
    const void* W2 = d_in[4];
    const void* b2 = d_in[5];

    int N = in_sizes[0] / 256;          // 50000
    int E = in_sizes[1] / 2;            // 1600000

    char* p = (char*)d_ws;
    auto alloc = [&](size_t bytes) {
        char* r = p;
        p += (bytes + 255) & ~(size_t)255;
        return r;
    };
    int*            flags  = (int*)alloc(8);
    int*            deg    = (int*)alloc((size_t)N * 4);
    int*            cursor = (int*)alloc((size_t)N * 4);
    int*            offs   = (int*)alloc(((size_t)N + 1) * 4);
    float*          dinv   = (float*)alloc((size_t)N * 4);
    unsigned short* cW1    = (unsigned short*)alloc(256 * 256 * 2);
    unsigned short* cW2    = (unsigned short*)alloc(256 * 256 * 2);
    unsigned short* cb1    = (unsigned short*)alloc(256 * 2);
    unsigned short* cb2    = (unsigned short*)alloc(256 * 2);
    int*            csr    = (int*)alloc((size_t)E * 4);
    unsigned short* buf0   = (unsigned short*)alloc((size_t)N * 256 * 2);
    unsigned short* buf1   = (unsigned short*)alloc((size_t)N * 256 * 2);

    int nF = N * 256;                   // 12.8M dense elements
    int gE = (E + 255) / 256;
    int gF = (nF + 255) / 256;

    // 1) sentinel: out_size ushorts worth of 1.0-pattern (safe lower bound on buffer size)
    int nwords = out_size / 2;
    k_sentinel<<<(nwords + 255) / 256, 256, 0, stream>>>((unsigned*)d_out, nwords);

    // 2) dtype flags, CSR build
    k_flags<<<1, 64, 0, stream>>>((const unsigned*)x, ei, E, flags);
    k_zero<<<(N + 255) / 256, 256, 0, stream>>>(deg, N);
    k_count<<<gE, 256, 0, stream>>>(ei, E, flags, deg);
    k_scan<<<1, 256, 0, stream>>>(deg, offs, cursor, dinv, N);
    k_fill<<<gE, 256, 0, stream>>>(ei, E, flags, cursor, csr);

    // 3) normalize dense inputs to bf16 workspace
    k_cvt<<<gF, 256, 0, stream>>>(x, buf0, nF, flags);
    k_cvt<<<(65536 + 255) / 256, 256, 0, stream>>>(W1, cW1, 65536, flags);
    k_cvt<<<(65536 + 255) / 256, 256, 0, stream>>>(W2, cW2, 65536, flags);
    k_cvt<<<1, 256, 0, stream>>>(b1, cb1, 256, flags);
    k_cvt<<<1, 256, 0, stream>>>(b2, cb2, 256, flags);

    // 4) two GCN layers
    dim3 gg((N + 63) / 64, 4);
    k_gemm<<<gg, 256, 0, stream>>>(buf0, cW1, buf1, N);                     // XW1
    k_agg<<<(N + 3) / 4, 256, 0, stream>>>(buf1, csr, offs, dinv, cb1,
                                           (void*)buf0, 1, 0, flags, N);    // h (bf16)
    k_gemm<<<gg, 256, 0, stream>>>(buf0, cW2, buf1, N);                     // HW2
    k_agg<<<(N + 3) / 4, 256, 0, stream>>>(buf1, csr, offs, dinv, cb2,
                                           d_out, 0, 1, flags, N);          // final
}

// Round 5
// 922.989 us; speedup vs baseline: 1.2416x; 1.2416x over previous
//
#include <hip/hip_runtime.h>
#include <stdint.h>

typedef __attribute__((ext_vector_type(8))) short bf16x8;   // 8 bf16 = 4 VGPRs
typedef __attribute__((ext_vector_type(4))) float f32x4;

__device__ __forceinline__ float bf2f(unsigned short b) {
    union { unsigned u; float f; } c; c.u = ((unsigned)b) << 16; return c.f;
}
__device__ __forceinline__ unsigned short f2bf(float f) {
    union { float f; unsigned u; } c; c.f = f;
    unsigned u = c.u;
    u += 0x7fffu + ((u >> 16) & 1u);          // round-to-nearest-even
    return (unsigned short)(u >> 16);
}

// Keep the harness-named symbol just in case anything looks it up.
__global__ void GNNEncoder_317827579954_kernel() {}

__global__ void k_zero(int* __restrict__ p, int n) {
    int i = blockIdx.x * 256 + threadIdx.x;
    if (i < n) p[i] = 0;
}

// flags[0] = 1 if x is f32 (else bf16-packed); flags[1] = 1 if edge_index is int64.
__global__ void k_flags(const unsigned* __restrict__ x, const int* __restrict__ ei,
                        int E, int* __restrict__ flags) {
    if (threadIdx.x != 0 || blockIdx.x != 0) return;
    int plausible = 0;
    for (int i = 0; i < 256; ++i) {
        unsigned u = x[i] & 0xffffu;
        unsigned e = (u >> 7) & 0xffu;
        if ((e >= 100u && e <= 145u) || u == 0u) ++plausible;
    }
    flags[0] = (plausible >= 192) ? 0 : 1;   // 0 = bf16, 1 = f32
    int n = E < 128 ? E : 128;
    int is64 = 1;
    for (int i = 0; i < n; ++i) {
        if (ei[2 * i + 1] != 0) { is64 = 0; break; }
    }
    flags[1] = is64;
}

// Normalize any dense input into bf16 workspace.
__global__ void k_cvt(const void* __restrict__ in, unsigned short* __restrict__ out,
                      int n, const int* __restrict__ flags) {
    int i = blockIdx.x * 256 + threadIdx.x;
    if (i >= n) return;
    if (flags[0]) out[i] = f2bf(((const float*)in)[i]);
    else          out[i] = ((const unsigned short*)in)[i];
}

// W [k][n] -> Wt [n][k] (256x256 bf16)
__global__ void k_transpose(const unsigned short* __restrict__ W, unsigned short* __restrict__ Wt) {
    int k = blockIdx.x, n = threadIdx.x;
    Wt[n * 256 + k] = W[k * 256 + n];
}

// deg[v] = #(dst == v)
__global__ void k_count(const int* __restrict__ ei, int E, const int* __restrict__ flags,
                        int* __restrict__ deg) {
    int i = blockIdx.x * blockDim.x + threadIdx.x;
    if (i >= E) return;
    int d = flags[1] ? ei[2 * E + 2 * i] : ei[E + i];
    atomicAdd(&deg[d], 1);
}

// single-block exclusive scan -> offs, cursor, dinv = rsqrt(deg+1)
__global__ void k_scan(const int* __restrict__ deg, int* __restrict__ offs,
                       int* __restrict__ cursor, float* __restrict__ dinv, int N) {
    __shared__ int sums[256];
    __shared__ int pref[257];
    int t = threadIdx.x;
    int chunk = (N + 255) / 256;
    int lo = t * chunk;
    int hi = lo + chunk; if (hi > N) hi = N;
    int s = 0;
    for (int i = lo; i < hi; ++i) s += deg[i];
    sums[t] = s;
    __syncthreads();
    if (t == 0) {
        int run = 0;
        for (int i = 0; i < 256; ++i) { pref[i] = run; run += sums[i]; }
        pref[256] = run;
    }
    __syncthreads();
    int run = pref[t];
    for (int i = lo; i < hi; ++i) {
        offs[i] = run; cursor[i] = run;
        run += deg[i];
        dinv[i] = rsqrtf((float)(deg[i] + 1));   // +1 = self loop
    }
    if (t == 0) offs[N] = pref[256];
}

// counting-sort CSR fill: csr[slot(dst)] = src
__global__ void k_fill(const int* __restrict__ ei, int E, const int* __restrict__ flags,
                       int* __restrict__ cursor, int* __restrict__ csr) {
    int i = blockIdx.x * blockDim.x + threadIdx.x;
    if (i >= E) return;
    int s, d;
    if (flags[1]) { s = ei[2 * i];     d = ei[2 * E + 2 * i]; }
    else          { s = ei[i];         d = ei[E + i]; }
    int p = atomicAdd(&cursor[d], 1);
    csr[p] = s;
}

// C[M,256] = A[M,256] @ B[256,256] (Bt = B^T), bf16 in/out, fp32 acc, MFMA.
// 4 waves = 2x2 of 32x32 wave-tiles; fragments loaded direct from global
// (A rows stream; Bt is 128 KB, L2-resident).
__global__ __launch_bounds__(256) void k_gemm(const unsigned short* __restrict__ A,
                                              const unsigned short* __restrict__ Bt,
                                              unsigned short* __restrict__ C, int M) {
    int tid  = threadIdx.x;
    int lane = tid & 63;
    int wave = tid >> 6;
    int q = lane >> 4;                 // quad 0..3
    int r = lane & 15;
    int rowBase = blockIdx.x * 64 + (wave >> 1) * 32;
    int colBase = blockIdx.y * 64 + (wave & 1) * 32;

    f32x4 acc[2][2] = {};
    for (int kk = 0; kk < 256; kk += 32) {
        int k = kk + q * 8;            // A/B frag: [m|n = lane&15][k = quad*8 + j]
        bf16x8 a[2], b[2];
#pragma unroll
        for (int mt = 0; mt < 2; ++mt) {
            int row = rowBase + mt * 16 + r;
            row = row < M ? row : M - 1;                     // clamp; discarded on store
            a[mt] = *(const bf16x8*)(A + (size_t)row * 256 + k);
        }
#pragma unroll
        for (int nt = 0; nt < 2; ++nt) {
            int col = colBase + nt * 16 + r;
            b[nt] = *(const bf16x8*)(Bt + (size_t)col * 256 + k);
        }
#pragma unroll
        for (int mt = 0; mt < 2; ++mt)
#pragma unroll
            for (int nt = 0; nt < 2; ++nt)
                acc[mt][nt] = __builtin_amdgcn_mfma_f32_16x16x32_bf16(a[mt], b[nt], acc[mt][nt], 0, 0, 0);
    }
#pragma unroll
    for (int mt = 0; mt < 2; ++mt)
#pragma unroll
        for (int nt = 0; nt < 2; ++nt) {
            int col = colBase + nt * 16 + r;
#pragma unroll
            for (int r2 = 0; r2 < 4; ++r2) {
                int row = rowBase + mt * 16 + q * 4 + r2;    // C/D: col=lane&15, row=q*4+reg
                if (row < M) C[(size_t)row * 256 + col] = f2bf(acc[mt][nt][r2]);
            }
        }
}

// out[v] = dinv[v]*sum_e dinv[src]*XW[src] + dinv[v]^2*XW[v] + b  (+relu)
// final=0 -> bf16 store (internal); final=1 -> store per flags[0] (f32 or bf16).
__global__ __launch_bounds__(256) void k_agg(const unsigned short* __restrict__ XW,
                                             const int* __restrict__ csr,
                                             const int* __restrict__ offs,
                                             const float* __restrict__ dinv,
                                             const unsigned short* __restrict__ bias,
                                             void* __restrict__ out,
                                             int relu, int final_, const int* __restrict__ flags,
                                             int N) {
    int v = blockIdx.x * 4 + (threadIdx.x >> 6);
    if (v >= N) return;
    int lane = threadIdx.x & 63;
    int c = lane * 4;
    float a0 = 0.f, a1 = 0.f, a2 = 0.f, a3 = 0.f;
    int beg = offs[v], end = offs[v + 1];
    for (int e = beg; e < end; ++e) {
        int s = csr[e];
        float w = dinv[s];
        uint2 u = *(const uint2*)(XW + (size_t)s * 256 + c);
        a0 += w * bf2f((unsigned short)(u.x & 0xffffu));
        a1 += w * bf2f((unsigned short)(u.x >> 16));
        a2 += w * bf2f((unsigned short)(u.y & 0xffffu));
        a3 += w * bf2f((unsigned short)(u.y >> 16));
    }
    float dv = dinv[v];
    float dv2 = dv * dv;
    uint2 su = *(const uint2*)(XW + (size_t)v * 256 + c);
    float r0 = dv * a0 + dv2 * bf2f((unsigned short)(su.x & 0xffffu)) + bf2f(bias[c + 0]);
    float r1 = dv * a1 + dv2 * bf2f((unsigned short)(su.x >> 16))     + bf2f(bias[c + 1]);
    float r2 = dv * a2 + dv2 * bf2f((unsigned short)(su.y & 0xffffu)) + bf2f(bias[c + 2]);
    float r3 = dv * a3 + dv2 * bf2f((unsigned short)(su.y >> 16))     + bf2f(bias[c + 3]);
    if (relu) {
        r0 = fmaxf(r0, 0.f); r1 = fmaxf(r1, 0.f);
        r2 = fmaxf(r2, 0.f); r3 = fmaxf(r3, 0.f);
    }
    if (final_ && flags[0]) {
        float4 o; o.x = r0; o.y = r1; o.z = r2; o.w = r3;
        *(float4*)((float*)out + (size_t)v * 256 + c) = o;
    } else {
        uint2 o;
        o.x = (unsigned)f2bf(r0) | ((unsigned)f2bf(r1) << 16);
        o.y = (unsigned)f2bf(r2) | ((unsigned)f2bf(r3) << 16);
        *(uint2*)((unsigned short*)out + (size_t)v * 256 + c) = o;
    }
}

extern "C" void kernel_launch(void* const* d_in, const int* in_sizes, int n_in,
                              void* d_out, int out_size, void* d_ws, size_t ws_size,
                              hipStream_t stream) {
    (void)n_in; (void)out_size; (void)ws_size;
    const void* x  = d_in[0];
    const int*  ei = (const int*)d_in[1];
    const void* W1 = d_in[2];
    const void* b1 = d_in[3];
    const void* W2 = d_in[4];
    const void* b2 = d_in[5];

    int N = in_sizes[0] / 256;          // 50000
    int E = in_sizes[1] / 2;            // 1600000

    char* p = (char*)d_ws;
    auto alloc = [&](size_t bytes) {
        char* r = p;
        p += (bytes + 255) & ~(size_t)255;
        return r;
    };
    int*            flags  = (int*)alloc(8);
    int*            deg    = (int*)alloc((size_t)N * 4);
    int*            cursor = (int*)alloc((size_t)N * 4);
    int*            offs   = (int*)alloc(((size_t)N + 1) * 4);
    float*          dinv   = (float*)alloc((size_t)N * 4);
    unsigned short* cW1    = (unsigned short*)alloc(256 * 256 * 2);
    unsigned short* cW2    = (unsigned short*)alloc(256 * 256 * 2);
    unsigned short* wt1    = (unsigned short*)alloc(256 * 256 * 2);
    unsigned short* wt2    = (unsigned short*)alloc(256 * 256 * 2);
    unsigned short* cb1    = (unsigned short*)alloc(256 * 2);
    unsigned short* cb2    = (unsigned short*)alloc(256 * 2);
    int*            csr    = (int*)alloc((size_t)E * 4);
    unsigned short* buf0   = (unsigned short*)alloc((size_t)N * 256 * 2);
    unsigned short* buf1   = (unsigned short*)alloc((size_t)N * 256 * 2);

    int nF = N * 256;
    int gE = (E + 255) / 256;
    int gF = (nF + 255) / 256;

    // dtype flags, CSR build
    k_flags<<<1, 64, 0, stream>>>((const unsigned*)x, ei, E, flags);
    k_zero<<<(N + 255) / 256, 256, 0, stream>>>(deg, N);
    k_count<<<gE, 256, 0, stream>>>(ei, E, flags, deg);
    k_scan<<<1, 256, 0, stream>>>(deg, offs, cursor, dinv, N);
    k_fill<<<gE, 256, 0, stream>>>(ei, E, flags, cursor, csr);

    // normalize dense inputs to bf16; transpose weights for MFMA B-fragments
    k_cvt<<<gF, 256, 0, stream>>>(x, buf0, nF, flags);
    k_cvt<<<(65536 + 255) / 256, 256, 0, stream>>>(W1, cW1, 65536, flags);
    k_cvt<<<(65536 + 255) / 256, 256, 0, stream>>>(W2, cW2, 65536, flags);
    k_cvt<<<1, 256, 0, stream>>>(b1, cb1, 256, flags);
    k_cvt<<<1, 256, 0, stream>>>(b2, cb2, 256, flags);
    k_transpose<<<256, 256, 0, stream>>>(cW1, wt1);
    k_transpose<<<256, 256, 0, stream>>>(cW2, wt2);

    // two GCN layers
    dim3 gg((N + 63) / 64, 4);
    k_gemm<<<gg, 256, 0, stream>>>(buf0, wt1, buf1, N);                     // XW1
    k_agg<<<(N + 3) / 4, 256, 0, stream>>>(buf1, csr, offs, dinv, cb1,
                                           (void*)buf0, 1, 0, flags, N);    // h (bf16)
    k_gemm<<<gg, 256, 0, stream>>>(buf0, wt2, buf1, N);                     // HW2
    k_agg<<<(N + 3) / 4, 256, 0, stream>>>(buf1, csr, offs, dinv, cb2,
                                           d_out, 0, 1, flags, N);          // final
}